// Round 6
// baseline (692.054 us; speedup 1.0000x reference)
//
#include <hip/hip_runtime.h>

#define ZT 32768
#define THREADS 256

// y2[a,d,z] = sum_b x1[a,b,z] * ( sum_c x0[b,c,z] * x2[c,d,z] )
//
// R5 structure (z32 x d8 blocks, T in LDS) with raw-barrier pipeline:
// - s_barrier + lgkmcnt(0) only (NO vmcnt drain) -> register-destined global
//   loads stay outstanding across round barriers.
// - x2 (HBM-cold stream): 4-round-deep register prefetch ring.
// - x1 (phase B): 3-slot ring, phase B is barrier-free.
// - x0: 1 round ahead (L2-warm via dq-sibling reuse).
__global__ __launch_bounds__(THREADS, 4) void einnet_kernel(
    const float* __restrict__ x0,   // (b,c,Z)
    const float* __restrict__ x1,   // (a,b,Z)
    const float* __restrict__ x2,   // (c,d,Z)
    float* __restrict__ out)        // (a,d,Z)
{
    // [0..2047]: x2 ping-pong (2 x 1024 floats); [2048..10239]: T (8192 floats)
    __shared__ float lds[10240];

    const int tid = threadIdx.x;
    const int bid = blockIdx.x;
    const int zc  = ((bid >> 5) << 3) | (bid & 7);   // 4 same-z blocks -> same XCD
    const int dq  = (bid >> 3) & 3;
    const int z0  = zc * 32;
    const int d0  = dq * 8;
    const int zl  = tid & 31;
    const int grp = tid >> 5;          // 0..7

    // x2 gather slot: one float4 (4 consecutive d-rows) per tile per thread
    const int s_cl = tid >> 6;         // 0..3  c within tile
    const int s_d4 = (tid >> 5) & 1;   // 0..1  d-float4
    const int s_zs = tid & 31;
    const int x2off = (s_cl * 32 + d0 + s_d4 * 4) * ZT + z0 + s_zs;
    const int s_w   = ((s_cl * 2 + s_d4) * 32 + s_zs) * 4;

    const int x0off = (grp * 4) * 32 * ZT + z0 + zl;   // b = 4*grp, c = 0
    const int x1off = x0off;                            // a = 4*grp, b = 0 (same shape)

    float4 v4[4];          // x2 prefetch ring (4 rounds deep)
    float  x0r[2][4][4];   // [parity][bb][cl]
    float  x1r[3][4][4];   // [ring][aa][bl]
    float  Ta[4][8];

    #pragma unroll
    for (int b = 0; b < 4; ++b)
        #pragma unroll
        for (int d = 0; d < 8; ++d) Ta[b][d] = 0.f;

    // ---- helpers (inline with literal args under #pragma unroll)
    auto GATHER = [&](int t, int slot) {
        const int g = x2off + t * 128 * ZT;
        v4[slot].x = x2[g];
        v4[slot].y = x2[g + ZT];
        v4[slot].z = x2[g + 2 * ZT];
        v4[slot].w = x2[g + 3 * ZT];
    };
    auto X0LOAD = [&](int t, int p) {
        #pragma unroll
        for (int bb = 0; bb < 4; ++bb)
            #pragma unroll
            for (int cl = 0; cl < 4; ++cl)
                x0r[p][bb][cl] = x0[x0off + (bb * 32 + t * 4 + cl) * ZT];
    };
    auto X1LOAD = [&](int t, int s) {
        #pragma unroll
        for (int aa = 0; aa < 4; ++aa)
            #pragma unroll
            for (int bl = 0; bl < 4; ++bl)
                x1r[s][aa][bl] = x1[x1off + (aa * 32 + t * 4 + bl) * ZT];
    };

    #define BARRIER_LGKM() do {                                   \
        asm volatile("s_waitcnt lgkmcnt(0)" ::: "memory");        \
        __builtin_amdgcn_s_barrier();                             \
        asm volatile("" ::: "memory");                            \
    } while (0)

    // ================= prologue: tiles 0..3 in flight =================
    GATHER(0, 0); GATHER(1, 1); GATHER(2, 2); GATHER(3, 3);
    X0LOAD(0, 0);
    *reinterpret_cast<float4*>(&lds[s_w]) = v4[0];   // compiler waits v4[0] only
    BARRIER_LGKM();

    // ================= phase A: 8 rounds =================
    #pragma unroll
    for (int t = 0; t < 8; ++t) {
        if (t < 4) GATHER(t + 4, t & 3);      // slot (t+4)&3 == t&3, freed last round
        if (t < 7) X0LOAD(t + 1, (t + 1) & 1);
        if (t == 6) X1LOAD(0, 0);             // pre-issue phase-B stream
        if (t == 7) X1LOAD(1, 1);

        const float* buf = &lds[(t & 1) * 1024];
        #pragma unroll
        for (int cl = 0; cl < 4; ++cl) {
            #pragma unroll
            for (int d4 = 0; d4 < 2; ++d4) {
                float4 s = *reinterpret_cast<const float4*>(
                    &buf[((cl * 2 + d4) * 32 + zl) * 4]);
                #pragma unroll
                for (int bb = 0; bb < 4; ++bb) {
                    const float xv = x0r[t & 1][bb][cl];
                    Ta[bb][d4 * 4 + 0] = fmaf(xv, s.x, Ta[bb][d4 * 4 + 0]);
                    Ta[bb][d4 * 4 + 1] = fmaf(xv, s.y, Ta[bb][d4 * 4 + 1]);
                    Ta[bb][d4 * 4 + 2] = fmaf(xv, s.z, Ta[bb][d4 * 4 + 2]);
                    Ta[bb][d4 * 4 + 3] = fmaf(xv, s.w, Ta[bb][d4 * 4 + 3]);
                }
            }
        }

        if (t < 7) {
            // stage tile t+1 (compiler inserts vmcnt for v4[(t+1)&3] only;
            // deeper prefetches stay outstanding across the barrier)
            *reinterpret_cast<float4*>(&lds[((t + 1) & 1) * 1024 + s_w]) = v4[(t + 1) & 3];
            BARRIER_LGKM();
        }
    }

    // ================= transition: T -> LDS =================
    #pragma unroll
    for (int bb = 0; bb < 4; ++bb) {
        #pragma unroll
        for (int d4 = 0; d4 < 2; ++d4) {
            float4 w;
            w.x = Ta[bb][d4 * 4 + 0]; w.y = Ta[bb][d4 * 4 + 1];
            w.z = Ta[bb][d4 * 4 + 2]; w.w = Ta[bb][d4 * 4 + 3];
            *reinterpret_cast<float4*>(
                &lds[2048 + (((grp * 4 + bb) * 2 + d4) * 32 + zl) * 4]) = w;
        }
    }
    BARRIER_LGKM();

    // ================= phase B: 8 rounds, barrier-free =================
    float y2[4][8];
    #pragma unroll
    for (int a = 0; a < 4; ++a)
        #pragma unroll
        for (int d = 0; d < 8; ++d) y2[a][d] = 0.f;

    #pragma unroll
    for (int u = 0; u < 8; ++u) {
        if (u < 6) X1LOAD(u + 2, (u + 2) % 3);

        #pragma unroll
        for (int bl = 0; bl < 4; ++bl) {
            #pragma unroll
            for (int d4 = 0; d4 < 2; ++d4) {
                float4 s = *reinterpret_cast<const float4*>(
                    &lds[2048 + (((u * 4 + bl) * 2 + d4) * 32 + zl) * 4]);
                #pragma unroll
                for (int aa = 0; aa < 4; ++aa) {
                    const float xv = x1r[u % 3][aa][bl];
                    y2[aa][d4 * 4 + 0] = fmaf(xv, s.x, y2[aa][d4 * 4 + 0]);
                    y2[aa][d4 * 4 + 1] = fmaf(xv, s.y, y2[aa][d4 * 4 + 1]);
                    y2[aa][d4 * 4 + 2] = fmaf(xv, s.z, y2[aa][d4 * 4 + 2]);
                    y2[aa][d4 * 4 + 3] = fmaf(xv, s.w, y2[aa][d4 * 4 + 3]);
                }
            }
        }
    }

    // ---- store: 128 B segments per (a,d) row
    const int oBase = (grp * 4) * 32 * ZT + d0 * ZT + z0 + zl;
    #pragma unroll
    for (int aa = 0; aa < 4; ++aa)
        #pragma unroll
        for (int dd = 0; dd < 8; ++dd)
            out[oBase + (aa * 32 + dd) * ZT] = y2[aa][dd];
}

extern "C" void kernel_launch(void* const* d_in, const int* in_sizes, int n_in,
                              void* d_out, int out_size, void* d_ws, size_t ws_size,
                              hipStream_t stream) {
    const float* x0 = (const float*)d_in[0];  // (b,c,Z)
    const float* x1 = (const float*)d_in[1];  // (a,b,Z)
    const float* x2 = (const float*)d_in[2];  // (c,d,Z)
    float* out = (float*)d_out;

    dim3 grid(4096);   // 1024 z-chunks x 4 d-quarters
    dim3 block(THREADS);
    hipLaunchKernelGGL(einnet_kernel, grid, block, 0, stream, x0, x1, x2, out);
}

// Round 7
// 380.985 us; speedup vs baseline: 1.8165x; 1.8165x over previous
//
#include <hip/hip_runtime.h>

#define ZT 32768
#define THREADS 256

// y2[a,d,z] = sum_b x1[a,b,z] * ( sum_c x0[b,c,z] * x2[c,d,z] )
//
// Block = (z-chunk 32) x (d-quarter 8). Phase A: T[32b x 8d x 32z] (LDS, 32KB)
// accumulated 2 c-columns per round (16 rounds); phase B: y2 = X1.T, 2 b per
// round. ALL staging via global_load_lds (zero registers): 4-slot x 10KB ring,
// ONE barrier per round, counted vmcnt (20/18/16/8 -> tile waited on has been
// in flight 3 rounds). Per-thread live set ~= 32 acc -> no spill.
#define GLDS(src, dst) __builtin_amdgcn_global_load_lds( \
    (const __attribute__((address_space(1))) void*)(src), \
    (__attribute__((address_space(3))) void*)(dst), 4, 0, 0)

#define WAITB(N) do { \
    asm volatile("s_waitcnt vmcnt(" #N ") lgkmcnt(0)" ::: "memory"); \
    __builtin_amdgcn_s_barrier(); \
    asm volatile("" ::: "memory"); \
} while (0)

__global__ __launch_bounds__(THREADS, 2) void einnet_kernel(
    const float* __restrict__ x0,   // (b,c,Z)
    const float* __restrict__ x1,   // (a,b,Z)
    const float* __restrict__ x2,   // (c,d,Z)
    float* __restrict__ out)        // (a,d,Z)
{
    // 4 staging slots x 2560 floats (x2-part 512 + x0/x1-part 2048) = 40 KB,
    // then T at [10240, 18432) = 32 KB. Total 72 KB -> 2 blocks/CU.
    __shared__ float lds[18432];

    const int tid  = threadIdx.x;
    const int lane = tid & 63;
    const int wv   = tid >> 6;          // wave 0..3
    const int bid  = blockIdx.x;
    const int zc   = ((bid >> 5) << 3) | (bid & 7);   // 4 same-z blocks -> same XCD
    const int dq   = (bid >> 3) & 3;
    const int z0   = zc * 32;
    const int d0   = dq * 8;
    const int zl   = tid & 31;
    const int grp  = tid >> 5;          // 0..7

    // per-lane source swizzles (LDS dest is linear: uniform base + lane*4)
    const int inv0 = (lane & 3) * ZT + (lane >> 2);           // x2: d-sub, z-sub
    const int inv1 = (lane >> 5) * 32 * ZT + (lane & 31);     // x0/x1: row-sub, z

    // wave-level source bases
    const float* x2b = x2 + ((wv >> 1) * 32 + 0) * ZT + (d0 + (wv & 1) * 4) * ZT + z0 + inv0;
    const float* x0b = x0 + (wv & 1) * 16 * 32 * ZT + (wv >> 1) * ZT + z0 + inv1;
    const float* x1b = x1 + (wv & 1) * 16 * 32 * ZT + (wv >> 1) * ZT + z0 + inv1;

    // A-tile t: c = {2t, 2t+1}; 2 x2-loads + 8 x0-loads per wave (10 total)
    auto stageA = [&](int t, int s) {
        float* sb = &lds[s * 2560];
        const float* g2 = x2b + t * 64 * ZT;
        GLDS(g2,      sb + wv * 128);
        GLDS(g2 + 16, sb + wv * 128 + 64);
        const float* g0 = x0b + t * 2 * ZT;
        float* dp = sb + 512 + wv * 512;
        #pragma unroll
        for (int i = 0; i < 8; ++i)
            GLDS(g0 + i * 64 * ZT, dp + i * 64);
    };
    // B-tile u: b = {2u, 2u+1}; 8 x1-loads per wave
    auto stageB = [&](int u, int s) {
        const float* g1 = x1b + u * 2 * ZT;
        float* dp = &lds[s * 2560] + 512 + wv * 512;
        #pragma unroll
        for (int i = 0; i < 8; ++i)
            GLDS(g1 + i * 64 * ZT, dp + i * 64);
    };

    // ---------------- prologue: 3 A-tiles in flight ----------------
    stageA(0, 0); stageA(1, 1); stageA(2, 2);

    float Ta[4][8];
    #pragma unroll
    for (int b = 0; b < 4; ++b)
        #pragma unroll
        for (int d = 0; d < 8; ++d) Ta[b][d] = 0.f;

    // ---------------- phase A: 16 rounds ----------------
    #pragma unroll
    for (int t = 0; t < 16; ++t) {
        if (t < 14)      WAITB(20);   // A_t landed; A_{t+1},A_{t+2} in flight
        else if (t == 14) WAITB(18);  // tail: B-tiles are 8 loads
        else              WAITB(16);

        if (t < 13) stageA(t + 3, (t + 3) & 3);
        else        stageB(t - 13, (t + 3) & 3);   // pre-issue phase-B stream

        const float* sb = &lds[(t & 3) * 2560];
        float x0v[2][4];
        #pragma unroll
        for (int cl = 0; cl < 2; ++cl)
            #pragma unroll
            for (int bb = 0; bb < 4; ++bb)
                x0v[cl][bb] = sb[512 + cl * 1024 + (grp * 4 + bb) * 32 + zl];

        #pragma unroll
        for (int cl = 0; cl < 2; ++cl) {
            #pragma unroll
            for (int d4 = 0; d4 < 2; ++d4) {
                float4 s = *reinterpret_cast<const float4*>(
                    &sb[cl * 256 + d4 * 128 + zl * 4]);
                #pragma unroll
                for (int bb = 0; bb < 4; ++bb) {
                    Ta[bb][d4 * 4 + 0] = fmaf(x0v[cl][bb], s.x, Ta[bb][d4 * 4 + 0]);
                    Ta[bb][d4 * 4 + 1] = fmaf(x0v[cl][bb], s.y, Ta[bb][d4 * 4 + 1]);
                    Ta[bb][d4 * 4 + 2] = fmaf(x0v[cl][bb], s.z, Ta[bb][d4 * 4 + 2]);
                    Ta[bb][d4 * 4 + 3] = fmaf(x0v[cl][bb], s.w, Ta[bb][d4 * 4 + 3]);
                }
            }
        }
    }

    // ---------------- T -> LDS (published by next round's barrier) ----------------
    #pragma unroll
    for (int bb = 0; bb < 4; ++bb) {
        #pragma unroll
        for (int d4 = 0; d4 < 2; ++d4) {
            float4 w;
            w.x = Ta[bb][d4 * 4 + 0]; w.y = Ta[bb][d4 * 4 + 1];
            w.z = Ta[bb][d4 * 4 + 2]; w.w = Ta[bb][d4 * 4 + 3];
            *reinterpret_cast<float4*>(
                &lds[10240 + (grp * 4 + bb) * 256 + d4 * 128 + zl * 4]) = w;
        }
    }

    // ---------------- phase B: 16 rounds ----------------
    float y2[4][8];
    #pragma unroll
    for (int a = 0; a < 4; ++a)
        #pragma unroll
        for (int d = 0; d < 8; ++d) y2[a][d] = 0.f;

    #pragma unroll
    for (int u = 0; u < 16; ++u) {
        if (u < 14)      WAITB(16);   // B_u landed; B_{u+1},B_{u+2} in flight
        else if (u == 14) WAITB(8);
        else              WAITB(0);   // final drain

        if (u < 13) stageB(u + 3, (u + 3) & 3);

        const float* sb = &lds[(u & 3) * 2560];
        float x1v[2][4];
        #pragma unroll
        for (int bl = 0; bl < 2; ++bl)
            #pragma unroll
            for (int aa = 0; aa < 4; ++aa)
                x1v[bl][aa] = sb[512 + bl * 1024 + (grp * 4 + aa) * 32 + zl];

        #pragma unroll
        for (int bl = 0; bl < 2; ++bl) {
            #pragma unroll
            for (int d4 = 0; d4 < 2; ++d4) {
                float4 s = *reinterpret_cast<const float4*>(
                    &lds[10240 + (u * 2 + bl) * 256 + d4 * 128 + zl * 4]);
                #pragma unroll
                for (int aa = 0; aa < 4; ++aa) {
                    y2[aa][d4 * 4 + 0] = fmaf(x1v[bl][aa], s.x, y2[aa][d4 * 4 + 0]);
                    y2[aa][d4 * 4 + 1] = fmaf(x1v[bl][aa], s.y, y2[aa][d4 * 4 + 1]);
                    y2[aa][d4 * 4 + 2] = fmaf(x1v[bl][aa], s.z, y2[aa][d4 * 4 + 2]);
                    y2[aa][d4 * 4 + 3] = fmaf(x1v[bl][aa], s.w, y2[aa][d4 * 4 + 3]);
                }
            }
        }
    }

    // ---------------- store: 128 B segments per (a,d) row ----------------
    const int oBase = (grp * 4) * 32 * ZT + d0 * ZT + z0 + zl;
    #pragma unroll
    for (int aa = 0; aa < 4; ++aa)
        #pragma unroll
        for (int dd = 0; dd < 8; ++dd)
            out[oBase + (aa * 32 + dd) * ZT] = y2[aa][dd];
}

extern "C" void kernel_launch(void* const* d_in, const int* in_sizes, int n_in,
                              void* d_out, int out_size, void* d_ws, size_t ws_size,
                              hipStream_t stream) {
    const float* x0 = (const float*)d_in[0];  // (b,c,Z)
    const float* x1 = (const float*)d_in[1];  // (a,b,Z)
    const float* x2 = (const float*)d_in[2];  // (c,d,Z)
    float* out = (float*)d_out;

    dim3 grid(4096);   // 1024 z-chunks x 4 d-quarters
    dim3 block(THREADS);
    hipLaunchKernelGGL(einnet_kernel, grid, block, 0, stream, x0, x1, x2, out);
}

// Round 9
// 316.063 us; speedup vs baseline: 2.1896x; 1.2054x over previous
//
#include <hip/hip_runtime.h>

#define ZT 32768
#define THREADS 128

// y2[a,d,z] = sum_b x1[a,b,z] * ( sum_c x0[b,c,z] * x2[c,d,z] )
//
// Block = (z-chunk 32) x (d-quarter 8), 128 threads = 32z x 4 grp, each thread
// owns 8 rows x 8 cols (64 acc) -> ~1 B LDS-read per FMA. 32 rounds of 2
// k-columns: phase A (k=c, tiles 0..15: x0+x2), phase B (k=b, tiles 16..31:
// x1; T resident in LDS). Staging via global_load_lds (zero registers),
// 4-slot x 10KB ring staged 3 rounds ahead, ONE barrier per round, counted
// vmcnt (40/36/32/16, never 0 mid-loop).
//
// Slot layout (2560 floats):
//   [0..2048)    x0/x1 part: [32 rows][32 z][2 k]   (row = wv*16 + i)
//   [2048..2560) x2 part:    [2 c][2 n4][32 z][4 d] (c stride 256!)
#define GLDS(src, dst) __builtin_amdgcn_global_load_lds( \
    (const __attribute__((address_space(1))) void*)(src), \
    (__attribute__((address_space(3))) void*)(dst), 4, 0, 0)

#define WAITB(N) do { \
    asm volatile("s_waitcnt vmcnt(" #N ") lgkmcnt(0)" ::: "memory"); \
    __builtin_amdgcn_s_barrier(); \
    asm volatile("" ::: "memory"); \
} while (0)

__global__ __launch_bounds__(THREADS) void einnet_kernel(
    const float* __restrict__ x0,   // (b,c,Z)
    const float* __restrict__ x1,   // (a,b,Z)
    const float* __restrict__ x2,   // (c,d,Z)
    float* __restrict__ out)        // (a,d,Z)
{
    // 4 slots x 2560 floats = 40 KB; T at [10240, 18432) = 32 KB. 72 KB total.
    __shared__ float lds[18432];

    const int tid  = threadIdx.x;
    const int lane = tid & 63;
    const int wv   = tid >> 6;          // wave 0..1
    const int bid  = blockIdx.x;
    const int zc   = ((bid >> 5) << 3) | (bid & 7);   // 4 dq-siblings -> same XCD
    const int dq   = (bid >> 3) & 3;
    const int z0   = zc * 32;
    const int d0   = dq * 8;
    const int zl   = tid & 31;
    const int grp  = tid >> 5;          // 0..3 -> rows grp*8..+8

    // per-lane GLDS source bases (LDS dest stays wave-uniform linear)
    const float* px0 = x0 + z0 + (lane & 1) * ZT + (lane >> 1);   // k-sub, z-sub
    const float* px1 = x1 + z0 + (lane & 1) * ZT + (lane >> 1);
    const float* px2 = x2 + z0 + (lane & 3) * ZT + (lane >> 2);   // d-sub, z-sub

    // A-tile t (c-pair 2t): x0part + x2part; 20 GLDS per wave
    auto stageA = [&](int t) {
        float* sb = &lds[(t & 3) * 2560];
        const float* s0 = px0 + (size_t)(wv * 16 * 32 + 2 * t) * ZT;
        float* dst0 = sb + wv * 1024;
        #pragma unroll
        for (int i = 0; i < 16; ++i)
            GLDS(s0 + (size_t)(i * 32) * ZT, dst0 + i * 64);
        const float* s2 = px2 + (size_t)((2 * t + wv) * 32 + d0) * ZT;
        float* dst2 = sb + 2048 + wv * 256;           // c stride 256
        #pragma unroll
        for (int j = 0; j < 4; ++j)      // n4 = j>>1, z-half = j&1
            GLDS(s2 + (size_t)((j >> 1) * 4) * ZT + (j & 1) * 16,
                 dst2 + (j >> 1) * 128 + (j & 1) * 64);
    };
    // B-tile tt (b-pair 2(tt-16)): x1part only; 16 GLDS per wave
    auto stageB = [&](int tt) {
        float* sb = &lds[(tt & 3) * 2560];
        const float* s1 = px1 + (size_t)(wv * 16 * 32 + 2 * (tt - 16)) * ZT;
        float* dst1 = sb + wv * 1024;
        #pragma unroll
        for (int i = 0; i < 16; ++i)
            GLDS(s1 + (size_t)(i * 32) * ZT, dst1 + i * 64);
    };

    float Ta[8][8];
    #pragma unroll
    for (int r = 0; r < 8; ++r)
        #pragma unroll
        for (int d = 0; d < 8; ++d) Ta[r][d] = 0.f;

    // ---------------- prologue: tiles 0,1,2 in flight ----------------
    stageA(0); stageA(1); stageA(2);

    // ---------------- phase A: rounds 0..12 ----------------
    #pragma unroll 1
    for (int t = 0; t < 13; ++t) {
        WAITB(40);                        // tile t landed; t+1,t+2 in flight
        stageA(t + 3);
        const float* sb = &lds[(t & 3) * 2560];
        float2 xv[8];
        #pragma unroll
        for (int r = 0; r < 8; ++r)
            xv[r] = *reinterpret_cast<const float2*>(&sb[(grp * 8 + r) * 64 + zl * 2]);
        float4 s2[2][2];
        #pragma unroll
        for (int c = 0; c < 2; ++c)
            #pragma unroll
            for (int n4 = 0; n4 < 2; ++n4)
                s2[c][n4] = *reinterpret_cast<const float4*>(
                    &sb[2048 + c * 256 + n4 * 128 + zl * 4]);
        #pragma unroll
        for (int c = 0; c < 2; ++c)
            #pragma unroll
            for (int n4 = 0; n4 < 2; ++n4)
                #pragma unroll
                for (int r = 0; r < 8; ++r) {
                    const float xc = (c == 0) ? xv[r].x : xv[r].y;
                    Ta[r][n4 * 4 + 0] = fmaf(xc, s2[c][n4].x, Ta[r][n4 * 4 + 0]);
                    Ta[r][n4 * 4 + 1] = fmaf(xc, s2[c][n4].y, Ta[r][n4 * 4 + 1]);
                    Ta[r][n4 * 4 + 2] = fmaf(xc, s2[c][n4].z, Ta[r][n4 * 4 + 2]);
                    Ta[r][n4 * 4 + 3] = fmaf(xc, s2[c][n4].w, Ta[r][n4 * 4 + 3]);
                }
    }

    // tail rounds 13,14,15: staging switches to B-tiles, vmcnt steps down
    #pragma unroll 1
    for (int t = 13; t < 16; ++t) {
        if (t == 13)      WAITB(40);
        else if (t == 14) WAITB(36);
        else              WAITB(32);
        stageB(t + 3);                    // tiles 16,17,18
        const float* sb = &lds[(t & 3) * 2560];
        float2 xv[8];
        #pragma unroll
        for (int r = 0; r < 8; ++r)
            xv[r] = *reinterpret_cast<const float2*>(&sb[(grp * 8 + r) * 64 + zl * 2]);
        float4 s2[2][2];
        #pragma unroll
        for (int c = 0; c < 2; ++c)
            #pragma unroll
            for (int n4 = 0; n4 < 2; ++n4)
                s2[c][n4] = *reinterpret_cast<const float4*>(
                    &sb[2048 + c * 256 + n4 * 128 + zl * 4]);
        #pragma unroll
        for (int c = 0; c < 2; ++c)
            #pragma unroll
            for (int n4 = 0; n4 < 2; ++n4)
                #pragma unroll
                for (int r = 0; r < 8; ++r) {
                    const float xc = (c == 0) ? xv[r].x : xv[r].y;
                    Ta[r][n4 * 4 + 0] = fmaf(xc, s2[c][n4].x, Ta[r][n4 * 4 + 0]);
                    Ta[r][n4 * 4 + 1] = fmaf(xc, s2[c][n4].y, Ta[r][n4 * 4 + 1]);
                    Ta[r][n4 * 4 + 2] = fmaf(xc, s2[c][n4].z, Ta[r][n4 * 4 + 2]);
                    Ta[r][n4 * 4 + 3] = fmaf(xc, s2[c][n4].w, Ta[r][n4 * 4 + 3]);
                }
    }

    // T -> LDS (published by round-16's lgkmcnt+barrier); Ta dies here
    #pragma unroll
    for (int r = 0; r < 8; ++r) {
        #pragma unroll
        for (int d4 = 0; d4 < 2; ++d4) {
            float4 w;
            w.x = Ta[r][d4 * 4 + 0]; w.y = Ta[r][d4 * 4 + 1];
            w.z = Ta[r][d4 * 4 + 2]; w.w = Ta[r][d4 * 4 + 3];
            *reinterpret_cast<float4*>(
                &lds[10240 + (grp * 8 + r) * 256 + d4 * 128 + zl * 4]) = w;
        }
    }

    float y2a[8][8];
    #pragma unroll
    for (int r = 0; r < 8; ++r)
        #pragma unroll
        for (int d = 0; d < 8; ++d) y2a[r][d] = 0.f;

    // ---------------- phase B: rounds 16..28 ----------------
    #pragma unroll 1
    for (int u = 16; u < 29; ++u) {
        WAITB(32);
        stageB(u + 3);                    // tiles 19..31
        const int kk = (u - 16) * 2;
        const float* sb = &lds[(u & 3) * 2560];
        float2 xv[8];
        #pragma unroll
        for (int r = 0; r < 8; ++r)
            xv[r] = *reinterpret_cast<const float2*>(&sb[(grp * 8 + r) * 64 + zl * 2]);
        float4 tv[2][2];
        #pragma unroll
        for (int k = 0; k < 2; ++k)
            #pragma unroll
            for (int d4 = 0; d4 < 2; ++d4)
                tv[k][d4] = *reinterpret_cast<const float4*>(
                    &lds[10240 + (kk + k) * 256 + d4 * 128 + zl * 4]);
        #pragma unroll
        for (int k = 0; k < 2; ++k)
            #pragma unroll
            for (int d4 = 0; d4 < 2; ++d4)
                #pragma unroll
                for (int r = 0; r < 8; ++r) {
                    const float xc = (k == 0) ? xv[r].x : xv[r].y;
                    y2a[r][d4 * 4 + 0] = fmaf(xc, tv[k][d4].x, y2a[r][d4 * 4 + 0]);
                    y2a[r][d4 * 4 + 1] = fmaf(xc, tv[k][d4].y, y2a[r][d4 * 4 + 1]);
                    y2a[r][d4 * 4 + 2] = fmaf(xc, tv[k][d4].z, y2a[r][d4 * 4 + 2]);
                    y2a[r][d4 * 4 + 3] = fmaf(xc, tv[k][d4].w, y2a[r][d4 * 4 + 3]);
                }
    }

    // tail rounds 29,30,31: no staging, vmcnt drains 32/16/0
    #pragma unroll 1
    for (int u = 29; u < 32; ++u) {
        if (u == 29)      WAITB(32);
        else if (u == 30) WAITB(16);
        else              WAITB(0);
        const int kk = (u - 16) * 2;
        const float* sb = &lds[(u & 3) * 2560];
        float2 xv[8];
        #pragma unroll
        for (int r = 0; r < 8; ++r)
            xv[r] = *reinterpret_cast<const float2*>(&sb[(grp * 8 + r) * 64 + zl * 2]);
        float4 tv[2][2];
        #pragma unroll
        for (int k = 0; k < 2; ++k)
            #pragma unroll
            for (int d4 = 0; d4 < 2; ++d4)
                tv[k][d4] = *reinterpret_cast<const float4*>(
                    &lds[10240 + (kk + k) * 256 + d4 * 128 + zl * 4]);
        #pragma unroll
        for (int k = 0; k < 2; ++k)
            #pragma unroll
            for (int d4 = 0; d4 < 2; ++d4)
                #pragma unroll
                for (int r = 0; r < 8; ++r) {
                    const float xc = (k == 0) ? xv[r].x : xv[r].y;
                    y2a[r][d4 * 4 + 0] = fmaf(xc, tv[k][d4].x, y2a[r][d4 * 4 + 0]);
                    y2a[r][d4 * 4 + 1] = fmaf(xc, tv[k][d4].y, y2a[r][d4 * 4 + 1]);
                    y2a[r][d4 * 4 + 2] = fmaf(xc, tv[k][d4].z, y2a[r][d4 * 4 + 2]);
                    y2a[r][d4 * 4 + 3] = fmaf(xc, tv[k][d4].w, y2a[r][d4 * 4 + 3]);
                }
    }

    // ---------------- store: 128 B segments per (a,d) row ----------------
    #pragma unroll
    for (int r = 0; r < 8; ++r) {
        const int a = grp * 8 + r;
        #pragma unroll
        for (int dd = 0; dd < 8; ++dd)
            out[(size_t)(a * 32 + d0 + dd) * ZT + z0 + zl] = y2a[r][dd];
    }
}

extern "C" void kernel_launch(void* const* d_in, const int* in_sizes, int n_in,
                              void* d_out, int out_size, void* d_ws, size_t ws_size,
                              hipStream_t stream) {
    const float* x0 = (const float*)d_in[0];  // (b,c,Z)
    const float* x1 = (const float*)d_in[1];  // (a,b,Z)
    const float* x2 = (const float*)d_in[2];  // (c,d,Z)
    float* out = (float*)d_out;

    dim3 grid(4096);   // 1024 z-chunks x 4 d-quarters
    dim3 block(THREADS);
    hipLaunchKernelGGL(einnet_kernel, grid, block, 0, stream, x0, x1, x2, out);
}

// Round 10
// 246.565 us; speedup vs baseline: 2.8068x; 1.2819x over previous
//
#include <hip/hip_runtime.h>

#define ZT 32768
#define ZTL ((size_t)ZT)
#define THREADS 256

// y2[a,d,z] = sum_b x1[a,b,z] * ( sum_c x0[b,c,z] * x2[c,d,z] )
//
// Exactly R5's structure (249 us, VGPR 64, 4 blocks/CU): z32 x d8 blocks,
// T in LDS, x2 ping-pong staged via registers, x0/x1 streamed 1 round ahead.
// ONE change: __syncthreads() -> s_barrier + lgkmcnt(0) only. The per-round
// vmcnt(0) drain was flushing the 1-round-ahead register prefetches (x2 v,
// x0 xn, x1 xa); with the raw barrier they stay outstanding and the compiler
// waits at use-site with exact counts. LDS hazards (x2 slot write, T write)
// are covered by lgkmcnt(0) + barrier.
#define BARRIER_LGKM() do {                                   \
    asm volatile("s_waitcnt lgkmcnt(0)" ::: "memory");        \
    __builtin_amdgcn_s_barrier();                             \
    asm volatile("" ::: "memory");                            \
} while (0)

__global__ __launch_bounds__(THREADS, 4) void einnet_kernel(
    const float* __restrict__ x0,   // (b,c,Z)
    const float* __restrict__ x1,   // (a,b,Z)
    const float* __restrict__ x2,   // (c,d,Z)
    float* __restrict__ out)        // (a,d,Z)
{
    // [0..2047]: x2 ping-pong (2 x 1024 floats); [2048..10239]: T (8192 floats)
    __shared__ float lds[10240];

    const int tid = threadIdx.x;
    const int bid = blockIdx.x;
    const int zc  = ((bid >> 5) << 3) | (bid & 7);   // 4 same-z blocks -> same XCD
    const int dq  = (bid >> 3) & 3;
    const int z0  = zc * 32;
    const int d0  = dq * 8;
    const int zl  = tid & 31;
    const int grp = tid >> 5;          // 0..7

    // ---- x2 gather slot: one float4 per tile per thread
    const int s_cl = tid >> 6;         // 0..3  c within tile
    const int s_d4 = (tid >> 5) & 1;   // 0..1  d-float4
    const int s_zs = tid & 31;
    const float* x2g = x2 + (size_t)(s_cl * 32 + d0 + s_d4 * 4) * ZTL + z0 + s_zs;
    const int s_w = ((s_cl * 2 + s_d4) * 32 + s_zs) * 4;   // lds word in buf

    // =================== phase A: T = X0 . X2 (d-slice) ===================
    float Ta[4][8];
    #pragma unroll
    for (int b = 0; b < 4; ++b)
        #pragma unroll
        for (int d = 0; d < 8; ++d) Ta[b][d] = 0.f;

    float xf[4][4], xn[4][4];
    float4 v;

    const float* x0b = x0 + (size_t)(grp * 4) * 32 * ZTL + z0 + zl;  // b=4grp, c=0

    // prologue: tile 0
    v.x = x2g[0]; v.y = x2g[ZTL]; v.z = x2g[2 * ZTL]; v.w = x2g[3 * ZTL];
    #pragma unroll
    for (int bb = 0; bb < 4; ++bb)
        #pragma unroll
        for (int cl = 0; cl < 4; ++cl)
            xf[bb][cl] = x0b[(size_t)(bb * 32 + cl) * ZTL];
    *reinterpret_cast<float4*>(&lds[s_w]) = v;
    BARRIER_LGKM();

    #pragma unroll 1
    for (int t = 0; t < 8; ++t) {
        if (t < 7) {   // issue next tile's global loads first (latency hides under compute)
            const float* g = x2g + (size_t)((t + 1) * 128) * ZTL;
            v.x = g[0]; v.y = g[ZTL]; v.z = g[2 * ZTL]; v.w = g[3 * ZTL];
            #pragma unroll
            for (int bb = 0; bb < 4; ++bb)
                #pragma unroll
                for (int cl = 0; cl < 4; ++cl)
                    xn[bb][cl] = x0b[(size_t)(bb * 32 + (t + 1) * 4 + cl) * ZTL];
        }

        const float* buf = &lds[(t & 1) * 1024];
        #pragma unroll
        for (int cl = 0; cl < 4; ++cl) {
            #pragma unroll
            for (int d4 = 0; d4 < 2; ++d4) {
                float4 s = *reinterpret_cast<const float4*>(
                    &buf[((cl * 2 + d4) * 32 + zl) * 4]);
                #pragma unroll
                for (int bb = 0; bb < 4; ++bb) {
                    Ta[bb][d4 * 4 + 0] = fmaf(xf[bb][cl], s.x, Ta[bb][d4 * 4 + 0]);
                    Ta[bb][d4 * 4 + 1] = fmaf(xf[bb][cl], s.y, Ta[bb][d4 * 4 + 1]);
                    Ta[bb][d4 * 4 + 2] = fmaf(xf[bb][cl], s.z, Ta[bb][d4 * 4 + 2]);
                    Ta[bb][d4 * 4 + 3] = fmaf(xf[bb][cl], s.w, Ta[bb][d4 * 4 + 3]);
                }
            }
        }

        if (t < 7) {
            *reinterpret_cast<float4*>(&lds[((t + 1) & 1) * 1024 + s_w]) = v;
            #pragma unroll
            for (int bb = 0; bb < 4; ++bb)
                #pragma unroll
                for (int cl = 0; cl < 4; ++cl)
                    xf[bb][cl] = xn[bb][cl];
        }
        BARRIER_LGKM();
    }

    // =================== transition: x1 prefetch, T -> LDS ===================
    float xa[4][4], xb[4][4];
    const float* x1b = x1 + (size_t)(grp * 4) * 32 * ZTL + z0 + zl;  // a=4grp, b=0
    #pragma unroll
    for (int aa = 0; aa < 4; ++aa)
        #pragma unroll
        for (int bl = 0; bl < 4; ++bl)
            xa[aa][bl] = x1b[(size_t)(aa * 32 + bl) * ZTL];

    #pragma unroll
    for (int bb = 0; bb < 4; ++bb) {
        #pragma unroll
        for (int d4 = 0; d4 < 2; ++d4) {
            float4 w;
            w.x = Ta[bb][d4 * 4 + 0]; w.y = Ta[bb][d4 * 4 + 1];
            w.z = Ta[bb][d4 * 4 + 2]; w.w = Ta[bb][d4 * 4 + 3];
            *reinterpret_cast<float4*>(
                &lds[2048 + (((grp * 4 + bb) * 2 + d4) * 32 + zl) * 4]) = w;
        }
    }
    BARRIER_LGKM();

    // =================== phase B: y2 = X1 . T (barrier-free) ===================
    float y2[4][8];
    #pragma unroll
    for (int a = 0; a < 4; ++a)
        #pragma unroll
        for (int d = 0; d < 8; ++d) y2[a][d] = 0.f;

    #pragma unroll
    for (int u = 0; u < 8; ++u) {
        if (u < 7) {
            #pragma unroll
            for (int aa = 0; aa < 4; ++aa)
                #pragma unroll
                for (int bl = 0; bl < 4; ++bl)
                    xb[aa][bl] = x1b[(size_t)(aa * 32 + (u + 1) * 4 + bl) * ZTL];
        }

        #pragma unroll
        for (int bl = 0; bl < 4; ++bl) {
            #pragma unroll
            for (int d4 = 0; d4 < 2; ++d4) {
                float4 s = *reinterpret_cast<const float4*>(
                    &lds[2048 + (((u * 4 + bl) * 2 + d4) * 32 + zl) * 4]);
                #pragma unroll
                for (int aa = 0; aa < 4; ++aa) {
                    y2[aa][d4 * 4 + 0] = fmaf(xa[aa][bl], s.x, y2[aa][d4 * 4 + 0]);
                    y2[aa][d4 * 4 + 1] = fmaf(xa[aa][bl], s.y, y2[aa][d4 * 4 + 1]);
                    y2[aa][d4 * 4 + 2] = fmaf(xa[aa][bl], s.z, y2[aa][d4 * 4 + 2]);
                    y2[aa][d4 * 4 + 3] = fmaf(xa[aa][bl], s.w, y2[aa][d4 * 4 + 3]);
                }
            }
        }

        if (u < 7) {
            #pragma unroll
            for (int aa = 0; aa < 4; ++aa)
                #pragma unroll
                for (int bl = 0; bl < 4; ++bl)
                    xa[aa][bl] = xb[aa][bl];
        }
    }

    // ---- store: 128 B segments per (a,d) row
    #pragma unroll
    for (int aa = 0; aa < 4; ++aa)
        #pragma unroll
        for (int dd = 0; dd < 8; ++dd)
            out[(size_t)((grp * 4 + aa) * 32 + d0 + dd) * ZTL + z0 + zl] = y2[aa][dd];
}

extern "C" void kernel_launch(void* const* d_in, const int* in_sizes, int n_in,
                              void* d_out, int out_size, void* d_ws, size_t ws_size,
                              hipStream_t stream) {
    const float* x0 = (const float*)d_in[0];  // (b,c,Z)
    const float* x1 = (const float*)d_in[1];  // (a,b,Z)
    const float* x2 = (const float*)d_in[2];  // (c,d,Z)
    float* out = (float*)d_out;

    dim3 grid(4096);   // 1024 z-chunks x 4 d-quarters
    dim3 block(THREADS);
    hipLaunchKernelGGL(einnet_kernel, grid, block, 0, stream, x0, x1, x2, out);
}